// Round 16
// baseline (82.760 us; speedup 1.0000x reference)
//
#include <hip/hip_runtime.h>
#include <hip/hip_bf16.h>
#include <hip/hip_fp8.h>

#define N_TOTAL 384
#define BS 128
#define PD 8
#define D_FEAT 131072
#define EPS 1e-6f

#define NSTRIP 256
#define COLS_PER (D_FEAT / NSTRIP)    // 512 cols per strip
#define CHUNK 64                      // 256 B per row per chunk
#define NCH (COLS_PER / CHUNK)        // 8 chunks per strip
#define NSWEEP 12                     // 512-thread sweeps per 96 KB chunk
#define NSLOT 24                      // subtile partials per block (all 24)
#define PSCALE 0.125f                 // pre-encode scale (avoid e4m3 saturation)

typedef __attribute__((ext_vector_type(4))) float f32x4;
typedef __attribute__((ext_vector_type(8))) __bf16 bf16x8;
typedef __attribute__((ext_vector_type(4))) __bf16 bf16x4;

typedef __attribute__((address_space(1))) const unsigned int gu32;
typedef __attribute__((address_space(3))) unsigned int lu32;

__device__ __forceinline__ void gload16(const void* g, void* l) {
    // async global->LDS DMA, 16 B/lane; LDS dest = wave-uniform base + lane*16
    __builtin_amdgcn_global_load_lds((gu32*)g, (lu32*)l, 16, 0, 0);
}

// Per-wave subtile tables: wave w owns 3 (A-band, B-band) pairs; first two share A.
static __device__ const int SAt[8][3] = {{0,0,0},{0,0,0},{1,1,1},{1,1,1},
                                         {2,2,4},{2,2,4},{3,3,5},{3,3,5}};
static __device__ const int SBt[8][3] = {{0,1,2},{3,4,5},{0,1,2},{3,4,5},
                                         {2,3,4},{4,5,5},{2,3,4},{4,5,5}};
// slot = wave*3 + s -> (row-band, col-band) for the reducer (flattened copies)
static __device__ const int SRB2[NSLOT] = {0,0,0, 0,0,0, 1,1,1, 1,1,1,
                                           2,2,4, 2,2,4, 3,3,5, 3,3,5};
static __device__ const int SCB2[NSLOT] = {0,1,2, 3,4,5, 0,1,2, 3,4,5,
                                           2,3,4, 4,5,5, 2,3,4, 4,5,5};

// Symmetric accessor: only the 24 stored subtiles of G are populated.
__device__ __forceinline__ float gsym(const float* __restrict__ G, int i, int j) {
    return ((i >> 7) <= (j >> 7)) ? G[(size_t)i * N_TOTAL + j]
                                  : G[(size_t)j * N_TOTAL + i];
}

// bf16 LDS fragment read: [384][128 B] rows, 16B-granule XOR swizzle
// phys_granule = logical_granule ^ (row & 7); fragment (ks,kg) = granule ks*4+kg.
__device__ __forceinline__ bf16x8 fragb(const char* smb, int row, int ks, int kg) {
    return *(const bf16x8*)(smb + row * 128 + ((((ks << 2) | kg) ^ (row & 7)) << 4));
}

// ---- stage A (R15 structure, fp8 partial output): X read ONCE ----
__global__ __launch_bounds__(512) void gram_fused_kernel(const float* __restrict__ X,
                                                         unsigned char* __restrict__ P) {
    __shared__ char smf[N_TOTAL * 256];   // 96 KB: fp32 [384][64 cols], linear (DMA dest)
    __shared__ char smb[N_TOTAL * 128];   // 48 KB: bf16 [384][64 cols], granule-swizzled

    const int strip = blockIdx.x;
    const int coff  = strip & (NCH - 1);   // chunk-order stagger (kept from R15)
    const int tid  = threadIdx.x;
    const int wave = tid >> 6;
    const int lane = tid & 63;
    const int r16  = lane & 15;
    const int kg   = lane >> 4;

    const int A0 = SAt[wave][0] * 64, A2 = SAt[wave][2] * 64;
    const int B0 = SBt[wave][0] * 64, B1 = SBt[wave][1] * 64, B2 = SBt[wave][2] * 64;

    const char* src0 = (const char*)X + (size_t)(tid >> 4) * (D_FEAT * 4)
                     + (size_t)strip * (COLS_PER * 4) + (tid & 15) * 16;

    const int cr   = tid >> 4;              // row within sweep block
    const int g16  = tid & 15;
    const int wswz = ((((g16 >> 1) ^ (cr & 7)) << 4) | ((g16 & 1) << 3));

    f32x4 acc0[4][4], acc1[4][4], acc2[4][4];
#pragma unroll
    for (int m = 0; m < 4; m++)
#pragma unroll
        for (int n = 0; n < 4; n++) {
            acc0[m][n] = (f32x4)(0.0f); acc1[m][n] = (f32x4)(0.0f); acc2[m][n] = (f32x4)(0.0f);
        }

#define STAGE(c)                                                                          \
    _Pragma("unroll") for (int s = 0; s < NSWEEP; s++)                                    \
        gload16(src0 + (size_t)s * (32ull * D_FEAT * 4) + (size_t)(c) * 256,              \
                smf + s * 8192 + tid * 16);

#define SUBT(accX, Bb, ks)                                                                \
    do {                                                                                  \
        bf16x8 bf[4];                                                                     \
        _Pragma("unroll") for (int n = 0; n < 4; n++)                                     \
            bf[n] = fragb(smb, (Bb) + n * 16 + r16, ks, kg);                              \
        _Pragma("unroll") for (int m = 0; m < 4; m++)                                     \
            _Pragma("unroll") for (int n = 0; n < 4; n++)                                 \
                accX[m][n] = __builtin_amdgcn_mfma_f32_16x16x32_bf16(af[m], bf[n],        \
                                                                     accX[m][n], 0, 0, 0);\
    } while (0)

    STAGE(coff);

    for (int t = 0; t < NCH; ++t) {
        asm volatile("s_waitcnt vmcnt(0)" ::: "memory");
        __builtin_amdgcn_sched_barrier(0);
        __builtin_amdgcn_s_barrier();
        __builtin_amdgcn_sched_barrier(0);

#pragma unroll
        for (int s = 0; s < NSWEEP; s++) {
            const f32x4 v = *(const f32x4*)(smf + s * 8192 + tid * 16);
            bf16x4 o;
            o[0] = (__bf16)v[0]; o[1] = (__bf16)v[1];
            o[2] = (__bf16)v[2]; o[3] = (__bf16)v[3];
            *(bf16x4*)(smb + (s * 32 + cr) * 128 + wswz) = o;
        }

        asm volatile("s_waitcnt lgkmcnt(0)" ::: "memory");
        __builtin_amdgcn_sched_barrier(0);
        __builtin_amdgcn_s_barrier();
        __builtin_amdgcn_sched_barrier(0);
        if (t + 1 < NCH) STAGE((t + 1 + coff) & (NCH - 1));

#pragma unroll
        for (int ks = 0; ks < 2; ++ks) {
            bf16x8 af[4];
#pragma unroll
            for (int m = 0; m < 4; m++) af[m] = fragb(smb, A0 + m * 16 + r16, ks, kg);
            SUBT(acc0, B0, ks);
            SUBT(acc1, B1, ks);
#pragma unroll
            for (int m = 0; m < 4; m++) af[m] = fragb(smb, A2 + m * 16 + r16, ks, kg);
            SUBT(acc2, B2, ks);
        }
    }
#undef STAGE
#undef SUBT

    // Epilogue: per-wave 64x64 partials as fp8 e4m3 (scaled x1/8), col-major u32 stores.
    // C/D layout: ccol = lane&15 (B-side), crow = (lane>>4)*4 + r (A-side).
    const int crow = (lane >> 4) * 4;
    const int ccol = lane & 15;
#define STOREP(accX, s)                                                                   \
    do {                                                                                  \
        unsigned char* base = P + ((size_t)strip * NSLOT + wave * 3 + (s)) * 4096;        \
        _Pragma("unroll") for (int m = 0; m < 4; m++)                                     \
            _Pragma("unroll") for (int n = 0; n < 4; n++) {                               \
                unsigned pk = 0;                                                          \
                _Pragma("unroll") for (int j = 0; j < 4; j++) {                           \
                    __hip_fp8_e4m3 h(accX[m][n][j] * PSCALE);                             \
                    pk |= (unsigned)h.__x << (8 * j);                                     \
                }                                                                         \
                *(unsigned*)(base + (n * 16 + ccol) * 64 + m * 16 + crow) = pk;           \
            }                                                                             \
    } while (0)
    STOREP(acc0, 0);
    STOREP(acc1, 1);
    STOREP(acc2, 2);
#undef STOREP
}

// ---- stage B: reduce fp8 partials over 256 strips -> G (fp32) ----
__global__ __launch_bounds__(128) void reduce_kernel(const unsigned char* __restrict__ P,
                                                     float* __restrict__ G) {
    const int gidx = blockIdx.x * 128 + threadIdx.x;   // 0..24575 (u32 groups)
    const int slot = gidx >> 10;                       // 0..23
    const int e4   = (gidx & 1023) * 4;                // elem index in subtile

    const unsigned char* p = P + (size_t)slot * 4096 + e4;
    float a0 = 0.f, a1 = 0.f, a2 = 0.f, a3 = 0.f;
#pragma unroll 8
    for (int strip = 0; strip < NSTRIP; ++strip) {
        const unsigned u = *(const unsigned*)(p + (size_t)strip * (NSLOT * 4096));
        __hip_fp8_e4m3 h0, h1, h2, h3;
        h0.__x = (unsigned char)(u);
        h1.__x = (unsigned char)(u >> 8);
        h2.__x = (unsigned char)(u >> 16);
        h3.__x = (unsigned char)(u >> 24);
        a0 += (float)h0; a1 += (float)h1; a2 += (float)h2; a3 += (float)h3;
    }

    const int rb  = SRB2[slot] * 64;
    const int cb  = SCB2[slot] * 64;
    const int col = e4 >> 6;                           // col-major: e = col*64 + row
    const int row = e4 & 63;                           // rows row..row+3 within column
    G[(size_t)(rb + row)     * N_TOTAL + cb + col] = a0 * 8.0f;
    G[(size_t)(rb + row + 1) * N_TOTAL + cb + col] = a1 * 8.0f;
    G[(size_t)(rb + row + 2) * N_TOTAL + cb + col] = a2 * 8.0f;
    G[(size_t)(rb + row + 3) * N_TOTAL + cb + col] = a3 * 8.0f;
}

// ---------------- denominators and loss ----------------
__global__ __launch_bounds__(128) void den_kernel(const float* __restrict__ G,
                                                  float* __restrict__ den) {
    const int i = blockIdx.x;
    __shared__ float sInv[N_TOTAL];
    for (int j = threadIdx.x; j < N_TOTAL; j += 128) {
        const float n = sqrtf(G[(size_t)j * N_TOTAL + j]);
        sInv[j] = 1.0f / fmaxf(n, EPS);
    }
    __syncthreads();

    const float mi  = sInv[i] * 10.0f;   // 1/temp = 10
    const int   myc = i & 7;
    float s = 0.0f;
    for (int j = threadIdx.x; j < N_TOTAL; j += 128) {
        if ((j & 7) != myc)
            s += expf(gsym(G, i, j) * mi * sInv[j]);
    }
#pragma unroll
    for (int off = 32; off > 0; off >>= 1) s += __shfl_down(s, off, 64);
    __shared__ float partial[2];
    if ((threadIdx.x & 63) == 0) partial[threadIdx.x >> 6] = s;
    __syncthreads();
    if (threadIdx.x == 0) den[i] = partial[0] + partial[1];
}

__global__ __launch_bounds__(256) void loss_kernel(const float* __restrict__ G,
                                                   const float* __restrict__ den,
                                                   float* __restrict__ out) {
    __shared__ float sInv[N_TOTAL];
    for (int j = threadIdx.x; j < N_TOTAL; j += 256) {
        const float n = sqrtf(G[(size_t)j * N_TOTAL + j]);
        sInv[j] = 1.0f / fmaxf(n, EPS);
    }
    __syncthreads();

    float s = 0.0f;
    for (int idx = threadIdx.x; idx < 7 * BS; idx += 256) {
        const int p   = idx & (BS - 1);
        const int set = idx >> 7;
        int a, b;
        switch (set) {
            case 0:  a = p;                        b = BS + p;                      break;
            case 1:  a = (p + PD) % N_TOTAL;       b = (BS + p + PD) % N_TOTAL;     break;
            case 2:  a = p;                        b = (p + PD) % N_TOTAL;          break;
            case 3:  a = BS + p;                   b = (BS + p + PD) % N_TOTAL;     break;
            case 4:  a = 2 * BS + p;               b = (2 * BS + p + PD) % N_TOTAL; break;
            case 5:  a = BS + p;                   b = 2 * BS + p;                  break;
            default: a = (BS + p + PD) % N_TOTAL;  b = (2 * BS + p + PD) % N_TOTAL; break;
        }
        const float en = expf(gsym(G, a, b) * sInv[a] * sInv[b] * 10.0f);
        s += log1pf(den[a] / en) + log1pf(den[b] / en);
    }
#pragma unroll
    for (int off = 32; off > 0; off >>= 1) s += __shfl_down(s, off, 64);
    __shared__ float partial[4];
    if ((threadIdx.x & 63) == 0) partial[threadIdx.x >> 6] = s;
    __syncthreads();
    if (threadIdx.x == 0)
        out[0] = (partial[0] + partial[1] + partial[2] + partial[3]) / 768.0f;
}

extern "C" void kernel_launch(void* const* d_in, const int* in_sizes, int n_in,
                              void* d_out, int out_size, void* d_ws, size_t ws_size,
                              hipStream_t stream) {
    (void)in_sizes; (void)n_in; (void)out_size; (void)ws_size;
    const float*   X   = (const float*)d_in[0];
    float*         out = (float*)d_out;
    float*         G   = (float*)d_ws;                            // 384*384 fp32
    float*         den = G + (size_t)N_TOTAL * N_TOTAL;           // 384 fp32
    unsigned char* P   = (unsigned char*)d_ws + (1u << 20);       // 256*24*4096 fp8 = 25 MB

    gram_fused_kernel<<<NSTRIP, 512, 0, stream>>>(X, P);
    reduce_kernel<<<192, 128, 0, stream>>>(P, G);
    den_kernel<<<N_TOTAL, 128, 0, stream>>>(G, den);
    loss_kernel<<<1, 256, 0, stream>>>(G, den, out);
}

// Round 17
// 71.067 us; speedup vs baseline: 1.1645x; 1.1645x over previous
//
#include <hip/hip_runtime.h>
#include <hip/hip_bf16.h>

#define N_TOTAL 384
#define BS 128
#define PD 8
#define D_FEAT 131072
#define EPS 1e-6f

#define NSTRIP 256
#define COLS_PER (D_FEAT / NSTRIP)    // 512 cols per strip
#define CHUNK 64                      // 256 B per row per chunk
#define NCH (COLS_PER / CHUNK)        // 8 chunks per strip
#define NSWEEP 12                     // 512-thread sweeps per 96 KB chunk
#define NSLOT 24                      // subtile partials per block (all 24)

typedef __attribute__((ext_vector_type(4))) float f32x4;
typedef __attribute__((ext_vector_type(8))) __bf16 bf16x8;
typedef __attribute__((ext_vector_type(4))) __bf16 bf16x4;

typedef __attribute__((address_space(1))) const unsigned int gu32;
typedef __attribute__((address_space(3))) unsigned int lu32;

__device__ __forceinline__ void gload16(const void* g, void* l) {
    // async global->LDS DMA, 16 B/lane; LDS dest = wave-uniform base + lane*16
    __builtin_amdgcn_global_load_lds((gu32*)g, (lu32*)l, 16, 0, 0);
}

// Per-wave subtile tables: wave w owns 3 (A-band, B-band) pairs; first two share A.
static __device__ const int SAt[8][3] = {{0,0,0},{0,0,0},{1,1,1},{1,1,1},
                                         {2,2,4},{2,2,4},{3,3,5},{3,3,5}};
static __device__ const int SBt[8][3] = {{0,1,2},{3,4,5},{0,1,2},{3,4,5},
                                         {2,3,4},{4,5,5},{2,3,4},{4,5,5}};
// slot = wave*3 + s -> (row-band, col-band) for the reducer (flattened copies)
static __device__ const int SRB2[NSLOT] = {0,0,0, 0,0,0, 1,1,1, 1,1,1,
                                           2,2,4, 2,2,4, 3,3,5, 3,3,5};
static __device__ const int SCB2[NSLOT] = {0,1,2, 3,4,5, 0,1,2, 3,4,5,
                                           2,3,4, 4,5,5, 2,3,4, 4,5,5};

// Symmetric accessor: only the 24 stored subtiles of G are populated.
__device__ __forceinline__ float gsym(const float* __restrict__ G, int i, int j) {
    return ((i >> 7) <= (j >> 7)) ? G[(size_t)i * N_TOTAL + j]
                                  : G[(size_t)j * N_TOTAL + i];
}

// bf16 LDS fragment read: [384][128 B] rows, 16B-granule XOR swizzle
// phys_granule = logical_granule ^ (row & 7); fragment (ks,kg) = granule ks*4+kg.
__device__ __forceinline__ bf16x8 fragb(const char* smb, int row, int ks, int kg) {
    return *(const bf16x8*)(smb + row * 128 + ((((ks << 2) | kg) ^ (row & 7)) << 4));
}

// ---- stage A (R13 + per-strip chunk-order stagger): X read ONCE, channel-spread ----
__global__ __launch_bounds__(512) void gram_fused_kernel(const float* __restrict__ X,
                                                         __bf16* __restrict__ P) {
    __shared__ char smf[N_TOTAL * 256];   // 96 KB: fp32 [384][64 cols], linear (DMA dest)
    __shared__ char smb[N_TOTAL * 128];   // 48 KB: bf16 [384][64 cols], granule-swizzled

    const int strip = blockIdx.x;
    const int coff  = strip & (NCH - 1);   // chunk-order stagger (channel de-aliasing)
    const int tid  = threadIdx.x;
    const int wave = tid >> 6;
    const int lane = tid & 63;
    const int r16  = lane & 15;
    const int kg   = lane >> 4;

    const int A0 = SAt[wave][0] * 64, A2 = SAt[wave][2] * 64;
    const int B0 = SBt[wave][0] * 64, B1 = SBt[wave][1] * 64, B2 = SBt[wave][2] * 64;

    const char* src0 = (const char*)X + (size_t)(tid >> 4) * (D_FEAT * 4)
                     + (size_t)strip * (COLS_PER * 4) + (tid & 15) * 16;

    const int cr   = tid >> 4;              // row within sweep block
    const int g16  = tid & 15;
    const int wswz = ((((g16 >> 1) ^ (cr & 7)) << 4) | ((g16 & 1) << 3));

    f32x4 acc0[4][4], acc1[4][4], acc2[4][4];
#pragma unroll
    for (int m = 0; m < 4; m++)
#pragma unroll
        for (int n = 0; n < 4; n++) {
            acc0[m][n] = (f32x4)(0.0f); acc1[m][n] = (f32x4)(0.0f); acc2[m][n] = (f32x4)(0.0f);
        }

#define STAGE(c)                                                                          \
    _Pragma("unroll") for (int s = 0; s < NSWEEP; s++)                                    \
        gload16(src0 + (size_t)s * (32ull * D_FEAT * 4) + (size_t)(c) * 256,              \
                smf + s * 8192 + tid * 16);

#define SUBT(accX, Bb, ks)                                                                \
    do {                                                                                  \
        bf16x8 bf[4];                                                                     \
        _Pragma("unroll") for (int n = 0; n < 4; n++)                                     \
            bf[n] = fragb(smb, (Bb) + n * 16 + r16, ks, kg);                              \
        _Pragma("unroll") for (int m = 0; m < 4; m++)                                     \
            _Pragma("unroll") for (int n = 0; n < 4; n++)                                 \
                accX[m][n] = __builtin_amdgcn_mfma_f32_16x16x32_bf16(af[m], bf[n],        \
                                                                     accX[m][n], 0, 0, 0);\
    } while (0)

    STAGE(coff);

    for (int t = 0; t < NCH; ++t) {
        asm volatile("s_waitcnt vmcnt(0)" ::: "memory");
        __builtin_amdgcn_sched_barrier(0);
        __builtin_amdgcn_s_barrier();
        __builtin_amdgcn_sched_barrier(0);

#pragma unroll
        for (int s = 0; s < NSWEEP; s++) {
            const f32x4 v = *(const f32x4*)(smf + s * 8192 + tid * 16);
            bf16x4 o;
            o[0] = (__bf16)v[0]; o[1] = (__bf16)v[1];
            o[2] = (__bf16)v[2]; o[3] = (__bf16)v[3];
            *(bf16x4*)(smb + (s * 32 + cr) * 128 + wswz) = o;
        }

        asm volatile("s_waitcnt lgkmcnt(0)" ::: "memory");
        __builtin_amdgcn_sched_barrier(0);
        __builtin_amdgcn_s_barrier();
        __builtin_amdgcn_sched_barrier(0);
        if (t + 1 < NCH) STAGE((t + 1 + coff) & (NCH - 1));

#pragma unroll
        for (int ks = 0; ks < 2; ++ks) {
            bf16x8 af[4];
#pragma unroll
            for (int m = 0; m < 4; m++) af[m] = fragb(smb, A0 + m * 16 + r16, ks, kg);
            SUBT(acc0, B0, ks);
            SUBT(acc1, B1, ks);
#pragma unroll
            for (int m = 0; m < 4; m++) af[m] = fragb(smb, A2 + m * 16 + r16, ks, kg);
            SUBT(acc2, B2, ks);
        }
    }
#undef STAGE
#undef SUBT

    const int crow = (lane >> 4) * 4;
    const int ccol = lane & 15;
#define STOREP(accX, s)                                                                   \
    do {                                                                                  \
        __bf16* base = P + ((size_t)strip * NSLOT + wave * 3 + (s)) * 4096;               \
        _Pragma("unroll") for (int m = 0; m < 4; m++)                                     \
            _Pragma("unroll") for (int n = 0; n < 4; n++) {                               \
                bf16x4 v;                                                                 \
                v[0] = (__bf16)accX[m][n][0]; v[1] = (__bf16)accX[m][n][1];               \
                v[2] = (__bf16)accX[m][n][2]; v[3] = (__bf16)accX[m][n][3];               \
                *(bf16x4*)(base + (n * 16 + ccol) * 64 + m * 16 + crow) = v;              \
            }                                                                             \
    } while (0)
    STOREP(acc0, 0);
    STOREP(acc1, 1);
    STOREP(acc2, 2);
#undef STOREP
}

// ---- stage B: reduce bf16 partials over 256 strips -> G (fp32), u32-vectorized ----
__global__ __launch_bounds__(128) void reduce_kernel(const __bf16* __restrict__ P,
                                                     float* __restrict__ G) {
    const int gidx = blockIdx.x * 128 + threadIdx.x;   // 0..49151 (pairs of elems)
    const int slot = gidx >> 11;                       // 0..23
    const int pe   = (gidx & 2047) * 2;                // even elem index in subtile

    const unsigned* p = (const unsigned*)(P + (size_t)slot * 4096 + pe);
    const size_t stride = (size_t)NSLOT * 4096 / 2;    // u32 stride per strip
    float s0 = 0.0f, s1 = 0.0f;
#pragma unroll 16
    for (int strip = 0; strip < NSTRIP; ++strip) {
        const unsigned u = p[stride * strip];
        s0 += __uint_as_float(u << 16);                // low bf16
        s1 += __uint_as_float(u & 0xffff0000u);        // high bf16
    }

    const int rb  = SRB2[slot] * 64;
    const int cb  = SCB2[slot] * 64;
    const int col = pe >> 6;                           // col-major subtile: e = col*64+row
    const int row = pe & 63;
    G[(size_t)(rb + row)     * N_TOTAL + cb + col] = s0;
    G[(size_t)(rb + row + 1) * N_TOTAL + cb + col] = s1;
}

// ---------------- denominators and loss ----------------
__global__ __launch_bounds__(128) void den_kernel(const float* __restrict__ G,
                                                  float* __restrict__ den) {
    const int i = blockIdx.x;
    __shared__ float sInv[N_TOTAL];
    for (int j = threadIdx.x; j < N_TOTAL; j += 128) {
        const float n = sqrtf(G[(size_t)j * N_TOTAL + j]);
        sInv[j] = 1.0f / fmaxf(n, EPS);
    }
    __syncthreads();

    const float mi  = sInv[i] * 10.0f;   // 1/temp = 10
    const int   myc = i & 7;
    float s = 0.0f;
    for (int j = threadIdx.x; j < N_TOTAL; j += 128) {
        if ((j & 7) != myc)
            s += expf(gsym(G, i, j) * mi * sInv[j]);
    }
#pragma unroll
    for (int off = 32; off > 0; off >>= 1) s += __shfl_down(s, off, 64);
    __shared__ float partial[2];
    if ((threadIdx.x & 63) == 0) partial[threadIdx.x >> 6] = s;
    __syncthreads();
    if (threadIdx.x == 0) den[i] = partial[0] + partial[1];
}

__global__ __launch_bounds__(256) void loss_kernel(const float* __restrict__ G,
                                                   const float* __restrict__ den,
                                                   float* __restrict__ out) {
    __shared__ float sInv[N_TOTAL];
    for (int j = threadIdx.x; j < N_TOTAL; j += 256) {
        const float n = sqrtf(G[(size_t)j * N_TOTAL + j]);
        sInv[j] = 1.0f / fmaxf(n, EPS);
    }
    __syncthreads();

    float s = 0.0f;
    for (int idx = threadIdx.x; idx < 7 * BS; idx += 256) {
        const int p   = idx & (BS - 1);
        const int set = idx >> 7;
        int a, b;
        switch (set) {
            case 0:  a = p;                        b = BS + p;                      break;
            case 1:  a = (p + PD) % N_TOTAL;       b = (BS + p + PD) % N_TOTAL;     break;
            case 2:  a = p;                        b = (p + PD) % N_TOTAL;          break;
            case 3:  a = BS + p;                   b = (BS + p + PD) % N_TOTAL;     break;
            case 4:  a = 2 * BS + p;               b = (2 * BS + p + PD) % N_TOTAL; break;
            case 5:  a = BS + p;                   b = 2 * BS + p;                  break;
            default: a = (BS + p + PD) % N_TOTAL;  b = (2 * BS + p + PD) % N_TOTAL; break;
        }
        const float en = expf(gsym(G, a, b) * sInv[a] * sInv[b] * 10.0f);
        s += log1pf(den[a] / en) + log1pf(den[b] / en);
    }
#pragma unroll
    for (int off = 32; off > 0; off >>= 1) s += __shfl_down(s, off, 64);
    __shared__ float partial[4];
    if ((threadIdx.x & 63) == 0) partial[threadIdx.x >> 6] = s;
    __syncthreads();
    if (threadIdx.x == 0)
        out[0] = (partial[0] + partial[1] + partial[2] + partial[3]) / 768.0f;
}

extern "C" void kernel_launch(void* const* d_in, const int* in_sizes, int n_in,
                              void* d_out, int out_size, void* d_ws, size_t ws_size,
                              hipStream_t stream) {
    (void)in_sizes; (void)n_in; (void)out_size; (void)ws_size;
    const float* X   = (const float*)d_in[0];
    float*       out = (float*)d_out;
    float*       G   = (float*)d_ws;                          // 384*384 fp32 (24 subtiles)
    float*       den = G + (size_t)N_TOTAL * N_TOTAL;         // 384 fp32
    __bf16*      P   = (__bf16*)((char*)d_ws + (1u << 20));   // 256*24*4096 bf16 = 50 MB

    gram_fused_kernel<<<NSTRIP, 512, 0, stream>>>(X, P);
    reduce_kernel<<<384, 128, 0, stream>>>(P, G);
    den_kernel<<<N_TOTAL, 128, 0, stream>>>(G, den);
    loss_kernel<<<1, 256, 0, stream>>>(G, den, out);
}